// Round 6
// baseline (1624.315 us; speedup 1.0000x reference)
//
#include <hip/hip_runtime.h>
#include <cstdint>
#include <cstddef>

#define NROWS 524288
#define DIN 14
#define HID 128
#define LAT 5
#define VOCAB 256
#define BR 128          // rows per block
#define NT 512          // threads per block
#define HS 129          // LDS stride for h tiles (bank-conflict padding)

// Zero-instruction fence: pins a float in a VGPR so the chain order is exact.
#define FENCE(v) asm volatile("" : "+v"(v))

// d_out layout (floats), concatenated reference outputs:
static constexpr size_t OUT_OFF  = 0;                       // output [N,14]
static constexpr size_t LOSS_OFF = 7340032;                 // quant_loss scalar
static constexpr size_t PERP_OFF = 7340033;                 // perplexity scalar
static constexpr size_t OH_OFF   = 7340034;                 // min_encodings [N,256]
static constexpr size_t IDX_OFF  = 141557762;               // min_encoding_indices [N,1]

// LDS layout (float offsets)
static constexpr int OFF_W2  = 0;                   // 128*128 = 16384
static constexpr int OFF_H   = OFF_W2 + HID*HID;    // 128*129 = 16512
static constexpr int OFF_W1  = OFF_H  + BR*HS;      // 14*128 = 1792 (dead after layer 1)
//   union over the W1 region (all first written AFTER layer 1 completes):
static constexpr int OFF_IDX = OFF_W1;              // 128 ints
static constexpr int OFF_HIST= OFF_W1 + BR;         // 256 uints
static constexpr int OFF_RED = OFF_HIST + VOCAB;    // 16 floats (400 <= 1792)
static constexpr int OFF_B1  = OFF_W1 + DIN*HID;    // 128
static constexpr int OFF_B2  = OFF_B1 + HID;        // 128
static constexpr int OFF_W3  = OFF_B2 + HID;        // 128*5 = 640
static constexpr int OFF_B3  = OFF_W3 + HID*LAT;    // 5 (pad 8)
static constexpr int OFF_EMB = OFF_B3 + 8;          // 256*5 = 1280
static constexpr int OFF_EE  = OFF_EMB + VOCAB*LAT; // 256 floats
static constexpr int OFF_DW1 = OFF_EE  + VOCAB;     // 5*128 = 640
static constexpr int OFF_DB1 = OFF_DW1 + LAT*HID;   // 128
static constexpr int OFF_DW2 = OFF_DB1 + HID;       // 128*14 = 1792
static constexpr int OFF_DB2 = OFF_DW2 + HID*DIN;   // 14 (pad 16)
static constexpr int OFF_Q   = OFF_DB2 + 16;        // 128*5 = 640
static constexpr int SMEM_FLOATS = OFF_Q + BR*LAT;
static constexpr int SMEM_BYTES  = SMEM_FLOATS * 4; // 161,376 B (< 160 KiB)
static_assert(SMEM_BYTES <= 160*1024, "LDS over budget");

__global__ __launch_bounds__(NT, 1)
void vqvae_main(const float* __restrict__ x,
                const float* __restrict__ ew1, const float* __restrict__ eb1,
                const float* __restrict__ ew2, const float* __restrict__ eb2,
                const float* __restrict__ ew3, const float* __restrict__ eb3,
                const float* __restrict__ emb,
                const float* __restrict__ dw1, const float* __restrict__ db1,
                const float* __restrict__ dw2, const float* __restrict__ db2,
                float* __restrict__ out,
                double* __restrict__ loss_sum,
                unsigned int* __restrict__ hist_g)
{
    #pragma clang fp contract(off)

    extern __shared__ float smem[];
    float* s_w2  = smem + OFF_W2;
    float* s_h   = smem + OFF_H;
    float* s_w1  = smem + OFF_W1;
    float* s_b1  = smem + OFF_B1;
    float* s_b2  = smem + OFF_B2;
    float* s_w3  = smem + OFF_W3;
    float* s_b3  = smem + OFF_B3;
    float* s_emb = smem + OFF_EMB;
    float* s_ee  = smem + OFF_EE;
    float* s_dw1 = smem + OFF_DW1;
    float* s_db1 = smem + OFF_DB1;
    float* s_dw2 = smem + OFF_DW2;
    float* s_db2 = smem + OFF_DB2;
    float* s_q   = smem + OFF_Q;
    int*   s_idx = reinterpret_cast<int*>(smem + OFF_IDX);
    unsigned int* s_hist = reinterpret_cast<unsigned int*>(smem + OFF_HIST);
    float* s_red = smem + OFF_RED;

    const int tid = threadIdx.x;
    const int r_base = blockIdx.x * BR;

    // ---- stage weights into LDS ----
    for (int i = tid; i < HID*HID/4; i += NT)
        reinterpret_cast<float4*>(s_w2)[i] = reinterpret_cast<const float4*>(ew2)[i];
    for (int i = tid; i < DIN*HID; i += NT) s_w1[i]  = ew1[i];
    for (int i = tid; i < HID*DIN; i += NT) s_dw2[i] = dw2[i];
    for (int i = tid; i < VOCAB*LAT; i += NT) s_emb[i] = emb[i];
    for (int i = tid; i < HID*LAT; i += NT) s_w3[i]  = ew3[i];
    for (int i = tid; i < LAT*HID; i += NT) s_dw1[i] = dw1[i];
    if (tid < HID) { s_b1[tid] = eb1[tid]; s_b2[tid] = eb2[tid]; s_db1[tid] = db1[tid]; }
    if (tid < LAT) s_b3[tid] = eb3[tid];
    if (tid < DIN) s_db2[tid] = db2[tid];
    __syncthreads();

    // ||emb||^2 per code — unfused products + sequential sum
    if (tid < VOCAB) {
        float p0 = s_emb[tid*LAT+0] * s_emb[tid*LAT+0];
        float p1 = s_emb[tid*LAT+1] * s_emb[tid*LAT+1];
        float p2 = s_emb[tid*LAT+2] * s_emb[tid*LAT+2];
        float p3 = s_emb[tid*LAT+3] * s_emb[tid*LAT+3];
        float p4 = s_emb[tid*LAT+4] * s_emb[tid*LAT+4];
        float e = p0 + p1; FENCE(e);
        e = e + p2; FENCE(e);
        e = e + p3; FENCE(e);
        e = e + p4; FENCE(e);
        s_ee[tid] = e;
    }

    // ---- layer 1: h1 = relu(x @ w1 + b1), single-acc ascending fmaf chain ----
    {
        const int r  = tid >> 2;     // 0..127
        const int q4 = tid & 3;      // col group (stride-4 cols -> conflict-free)
        const float* xrow = x + (size_t)(r_base + r) * DIN;
        float xr[DIN];
        #pragma unroll
        for (int k = 0; k < DIN; k += 2) {
            float2 v = *reinterpret_cast<const float2*>(xrow + k);
            xr[k] = v.x; xr[k+1] = v.y;
        }
        for (int cc = 0; cc < HID/4; ++cc) {
            const int c = q4 + 4*cc;
            float s = 0.f;
            #pragma unroll
            for (int k = 0; k < DIN; ++k) { s = fmaf(xr[k], s_w1[k*HID + c], s); FENCE(s); }
            s = s + s_b1[c]; FENCE(s);
            s_h[r*HS + c] = fmaxf(s, 0.f);
        }
    }
    __syncthreads();   // layer-1 done; s_w1 region is dead from here on

    // ---- layer 2: h2 = relu(h1 @ w2 + b2) ----
    // ROUND-6 DRAW: dual accumulators (even-k / odd-k), combined once at the end.
    {
        const int trow = tid >> 4;   // 0..31
        const int tcol = tid & 15;   // 0..15
        const int r0 = trow * 4, c0 = tcol * 8;
        float accE[4][8], accO[4][8];
        #pragma unroll
        for (int i = 0; i < 4; ++i)
            #pragma unroll
            for (int j = 0; j < 8; ++j) { accE[i][j] = 0.f; accO[i][j] = 0.f; }

        for (int k = 0; k < HID; k += 2) {
            float hvE[4], hvO[4];
            #pragma unroll
            for (int i = 0; i < 4; ++i) {
                hvE[i] = s_h[(r0+i)*HS + k];
                hvO[i] = s_h[(r0+i)*HS + k + 1];
            }
            float4 waE = *reinterpret_cast<const float4*>(&s_w2[k*HID + c0]);
            float4 wbE = *reinterpret_cast<const float4*>(&s_w2[k*HID + c0 + 4]);
            float4 waO = *reinterpret_cast<const float4*>(&s_w2[(k+1)*HID + c0]);
            float4 wbO = *reinterpret_cast<const float4*>(&s_w2[(k+1)*HID + c0 + 4]);
            float wE[8] = {waE.x, waE.y, waE.z, waE.w, wbE.x, wbE.y, wbE.z, wbE.w};
            float wO[8] = {waO.x, waO.y, waO.z, waO.w, wbO.x, wbO.y, wbO.z, wbO.w};
            #pragma unroll
            for (int i = 0; i < 4; ++i)
                #pragma unroll
                for (int j = 0; j < 8; ++j) {
                    accE[i][j] = fmaf(hvE[i], wE[j], accE[i][j]); FENCE(accE[i][j]);
                    accO[i][j] = fmaf(hvO[i], wO[j], accO[i][j]); FENCE(accO[i][j]);
                }
        }
        __syncthreads();   // all h1 reads complete before overwrite
        #pragma unroll
        for (int i = 0; i < 4; ++i)
            #pragma unroll
            for (int j = 0; j < 8; ++j) {
                const int c = c0 + j;
                float s = accE[i][j] + accO[i][j]; FENCE(s);
                s = s + s_b2[c]; FENCE(s);
                s_h[(r0+i)*HS + c] = fmaxf(s, 0.f);
            }
    }
    __syncthreads();

    // ---- layer 3: q = h2 @ w3 + b3, ascending single-acc chain (+ hist init) ----
    for (int oi = tid; oi < BR*LAT; oi += NT) {
        const int r = oi / LAT;
        const int c = oi - r*LAT;
        float s = 0.f;
        for (int k = 0; k < HID; ++k) { s = fmaf(s_h[r*HS + k], s_w3[k*LAT + c], s); FENCE(s); }
        s = s + s_b3[c]; FENCE(s);
        s_q[r*LAT + c] = s;
    }
    if (tid < VOCAB) s_hist[tid] = 0u;
    __syncthreads();

    // ---- VQ: argmin over 256 codes, 4 threads per row ----
    // ROUND-6 DRAW: dot chain DESCENDING k. Score = (qq - 2*dot) + ee, each op rounded.
    float loss_local = 0.f;
    {
        const int r  = tid >> 2;
        const int q4 = tid & 3;
        float qv[LAT];
        #pragma unroll
        for (int k = 0; k < LAT; ++k) qv[k] = s_q[r*LAT + k];

        float qp0 = qv[0]*qv[0];
        float qp1 = qv[1]*qv[1];
        float qp2 = qv[2]*qv[2];
        float qp3 = qv[3]*qv[3];
        float qp4 = qv[4]*qv[4];
        float qq = qp0 + qp1; FENCE(qq);
        qq = qq + qp2; FENCE(qq);
        qq = qq + qp3; FENCE(qq);
        qq = qq + qp4; FENCE(qq);

        float bd = 3.4e38f; int bv = VOCAB;
        for (int ii = 0; ii < VOCAB/4; ++ii) {
            const int v = q4 + 4*ii;   // interleaved -> distinct banks across quarters
            float dot = 0.f;
            #pragma unroll
            for (int k = LAT-1; k >= 0; --k) { dot = fmaf(qv[k], s_emb[v*LAT + k], dot); FENCE(dot); }
            float twodot = 2.0f * dot; FENCE(twodot);
            float t1 = qq - twodot; FENCE(t1);
            float sc = t1 + s_ee[v]; FENCE(sc);
            const bool better = (sc < bd) || (sc == bd && v < bv);
            bd = better ? sc : bd;
            bv = better ? v  : bv;
        }
        #pragma unroll
        for (int m = 1; m <= 2; m <<= 1) {   // reduce across the 4 lanes of this row
            const float od = __shfl_xor(bd, m);
            const int   ov = __shfl_xor(bv, m);
            const bool better = (od < bd) || (od == bd && ov < bv);
            bd = better ? od : bd;
            bv = better ? ov : bv;
        }
        if (q4 == 0) {
            s_idx[r] = bv;
            atomicAdd(&s_hist[bv], 1u);
            float ls = 0.f;
            #pragma unroll
            for (int k = 0; k < LAT; ++k) {
                const float d = qv[k] - s_emb[bv*LAT + k];
                ls = fmaf(d, d, ls);
            }
            loss_local = ls;
        }
    }

    // ---- block-reduce loss, flush hist ----
    {
        float s = loss_local;
        #pragma unroll
        for (int off = 32; off > 0; off >>= 1) s += __shfl_down(s, off);
        if ((tid & 63) == 0) s_red[tid >> 6] = s;
    }
    __syncthreads();
    if (tid == 0) {
        float s = 0.f;
        #pragma unroll
        for (int w = 0; w < NT/64; ++w) s += s_red[w];
        atomicAdd(loss_sum, (double)s);
    }
    if (tid < VOCAB) {
        const unsigned c = s_hist[tid];
        if (c) atomicAdd(&hist_g[tid], c);
    }

    // ---- one-hot write (coalesced float2) + indices ----
    {
        float* oh = out + OH_OFF;
        const int rr0 = tid >> 7;       // 0..3
        const int c0  = (tid & 127) * 2;
        for (int it = 0; it < BR/4; ++it) {
            const int r = it*4 + rr0;
            const int best = s_idx[r];
            float2 v;
            v.x = (c0     == best) ? 1.f : 0.f;
            v.y = (c0 + 1 == best) ? 1.f : 0.f;
            *reinterpret_cast<float2*>(oh + (size_t)(r_base + r)*VOCAB + c0) = v;
        }
        if (tid < BR) out[IDX_OFF + r_base + tid] = (float)s_idx[tid];
    }

    // ---- decoder layer 1: h3 = relu(qe @ dw1 + db1), qe = q + (e - q) ----
    for (int oi = tid; oi < BR*HID; oi += NT) {
        const int r = oi >> 7;
        const int c = oi & 127;
        const int best = s_idx[r];
        float s = 0.f;
        #pragma unroll
        for (int k = 0; k < LAT; ++k) {
            const float qv = s_q[r*LAT + k];
            const float ev = s_emb[best*LAT + k];
            const float val = qv + (ev - qv);   // straight-through, f32 rounding
            s = fmaf(val, s_dw1[k*HID + c], s);
        }
        s_h[r*HS + c] = fmaxf(s + s_db1[c], 0.f);
    }
    __syncthreads();

    // ---- decoder layer 2: out = h3 @ dw2 + db2 ----
    for (int oi = tid; oi < BR*DIN; oi += NT) {
        const int r = oi / DIN;
        const int c = oi - r*DIN;
        float s = 0.f;
        #pragma unroll 8
        for (int k = 0; k < HID; ++k)
            s = fmaf(s_h[r*HS + k], s_dw2[k*DIN + c], s);
        out[(size_t)r_base*DIN + oi] = s + s_db2[c];
    }
}

__global__ void vq_init(double* loss, unsigned int* hist)
{
    if (threadIdx.x == 0) *loss = 0.0;
    if (threadIdx.x < VOCAB) hist[threadIdx.x] = 0u;
}

__global__ void vq_final(const double* __restrict__ loss,
                         const unsigned int* __restrict__ hist,
                         float* __restrict__ out)
{
    #pragma clang fp contract(off)
    __shared__ float red[4];
    const int t = threadIdx.x;   // 256 threads
    const float em = (float)hist[t] / (float)NROWS;
    float s = em * logf(em + 1e-10f);
    #pragma unroll
    for (int off = 32; off > 0; off >>= 1) s += __shfl_down(s, off);
    if ((t & 63) == 0) red[t >> 6] = s;
    __syncthreads();
    if (t == 0) {
        const float tot = red[0] + red[1] + red[2] + red[3];
        out[PERP_OFF] = expf(-tot);
        out[LOSS_OFF] = 1.25f * (float)(*loss / (double)((size_t)NROWS * LAT));
    }
}

extern "C" void kernel_launch(void* const* d_in, const int* in_sizes, int n_in,
                              void* d_out, int out_size, void* d_ws, size_t ws_size,
                              hipStream_t stream)
{
    const float* x   = (const float*)d_in[0];
    const float* ew1 = (const float*)d_in[1];
    const float* eb1 = (const float*)d_in[2];
    const float* ew2 = (const float*)d_in[3];
    const float* eb2 = (const float*)d_in[4];
    const float* ew3 = (const float*)d_in[5];
    const float* eb3 = (const float*)d_in[6];
    const float* emb = (const float*)d_in[7];
    const float* dw1 = (const float*)d_in[8];
    const float* db1 = (const float*)d_in[9];
    const float* dw2 = (const float*)d_in[10];
    const float* db2 = (const float*)d_in[11];
    float* out = (float*)d_out;

    double* loss = (double*)d_ws;
    unsigned int* hist = (unsigned int*)((char*)d_ws + 8);

    hipFuncSetAttribute(reinterpret_cast<const void*>(vqvae_main),
                        hipFuncAttributeMaxDynamicSharedMemorySize, SMEM_BYTES);

    vq_init<<<1, 256, 0, stream>>>(loss, hist);
    vqvae_main<<<NROWS / BR, NT, SMEM_BYTES, stream>>>(
        x, ew1, eb1, ew2, eb2, ew3, eb3, emb, dw1, db1, dw2, db2,
        out, loss, hist);
    vq_final<<<1, 256, 0, stream>>>(loss, hist, out);
}

// Round 7
// 1199.803 us; speedup vs baseline: 1.3538x; 1.3538x over previous
//
#include <hip/hip_runtime.h>
#include <cstdint>
#include <cstddef>

#define NROWS 524288
#define DIN 14
#define HID 128
#define LAT 5
#define VOCAB 256
#define BR 128          // rows per block
#define NT 512          // threads per block
#define HS 132          // LDS stride for h tile (even + %4==0 -> b64/b128 aligned)

// Zero-instruction fence: pins a float in a VGPR so the chain order is exact.
#define FENCE(v) asm volatile("" : "+v"(v))

// d_out layout (floats), concatenated reference outputs:
static constexpr size_t LOSS_OFF = 7340032;                 // quant_loss scalar
static constexpr size_t PERP_OFF = 7340033;                 // perplexity scalar
static constexpr size_t OH_OFF   = 7340034;                 // min_encodings [N,256]
static constexpr size_t IDX_OFF  = 141557762;               // min_encoding_indices [N,1]

// ---- LDS layout (float offsets; all base offsets %4==0 for b128) ----
static constexpr int OFF_W2   = 0;                  // [128][128] f32
static constexpr int OFF_H    = 16384;              // [128][HS]  h tile
static constexpr int OFF_W1T  = 33280;              // [128 cols][16 k]  (dead after layer 1)
//   union inside the W1T region (all first written AFTER layer 1):
static constexpr int OFF_IDX  = 33280;              // 128 ints
static constexpr int OFF_HIST = 33408;              // 256 u32
static constexpr int OFF_RED  = 33664;              // 16 f
static constexpr int OFF_Q    = 33680;              // [128][5]
static constexpr int OFF_QE4  = 34320;              // [128][4]  (qe k=0..3, b128-readable)
static constexpr int OFF_QE1  = 34832;              // [128]     (qe k=4)
static constexpr int OFF_B1   = 35328;              // 128
static constexpr int OFF_B2   = 35456;              // 128
static constexpr int OFF_W3T  = 35584;              // [5][132]
static constexpr int OFF_B3   = 36244;              // 8
static constexpr int OFF_EMB8 = 36252;              // [256][8]: e0..e4, ee, pad, pad
static constexpr int OFF_DW1  = 38300;              // [5][128] (as input layout)
static constexpr int OFF_DB1  = 38940;              // 128
static constexpr int OFF_DW2T = 39068;              // [14][132]
static constexpr int OFF_DB2  = 40916;              // 16
static constexpr int SMEM_FLOATS = 40932;
static constexpr int SMEM_BYTES  = SMEM_FLOATS * 4; // 163,728 B <= 163,840
static_assert(SMEM_BYTES <= 160*1024, "LDS over budget");
static_assert(OFF_QE4 + 512 <= OFF_QE1 && OFF_QE1 + 128 <= 35328, "union overflow");
static_assert((OFF_H % 4) == 0 && (OFF_W1T % 4) == 0 && (OFF_W3T % 4) == 0 &&
              (OFF_EMB8 % 4) == 0 && (OFF_DW2T % 4) == 0 && (OFF_QE4 % 4) == 0, "align");

__global__ __launch_bounds__(NT, 1)
void vqvae_main(const float* __restrict__ x,
                const float* __restrict__ ew1, const float* __restrict__ eb1,
                const float* __restrict__ ew2, const float* __restrict__ eb2,
                const float* __restrict__ ew3, const float* __restrict__ eb3,
                const float* __restrict__ emb,
                const float* __restrict__ dw1, const float* __restrict__ db1,
                const float* __restrict__ dw2, const float* __restrict__ db2,
                float* __restrict__ out,
                double* __restrict__ loss_sum,
                unsigned int* __restrict__ hist_g)
{
    #pragma clang fp contract(off)

    extern __shared__ float smem[];
    float* s_w2   = smem + OFF_W2;
    float* s_h    = smem + OFF_H;
    float* s_w1t  = smem + OFF_W1T;
    float* s_b1   = smem + OFF_B1;
    float* s_b2   = smem + OFF_B2;
    float* s_w3t  = smem + OFF_W3T;
    float* s_b3   = smem + OFF_B3;
    float* s_emb8 = smem + OFF_EMB8;
    float* s_dw1  = smem + OFF_DW1;
    float* s_db1  = smem + OFF_DB1;
    float* s_dw2t = smem + OFF_DW2T;
    float* s_db2  = smem + OFF_DB2;
    float* s_q    = smem + OFF_Q;
    float* s_qe4  = smem + OFF_QE4;
    float* s_qe1  = smem + OFF_QE1;
    int*   s_idx  = reinterpret_cast<int*>(smem + OFF_IDX);
    unsigned int* s_hist = reinterpret_cast<unsigned int*>(smem + OFF_HIST);
    float* s_red  = smem + OFF_RED;

    const int tid = threadIdx.x;
    const int r_base = blockIdx.x * BR;

    // ---- stage weights into LDS (same VALUES as round 6; layouts repacked) ----
    for (int i = tid; i < HID*HID/4; i += NT)
        reinterpret_cast<float4*>(s_w2)[i] = reinterpret_cast<const float4*>(ew2)[i];
    for (int i = tid; i < DIN*HID; i += NT) {          // w1T[c][k]
        const int k = i >> 7, c = i & 127;
        s_w1t[c*16 + k] = ew1[i];
    }
    for (int i = tid; i < VOCAB*LAT; i += NT) {        // emb8[v][k]
        const int v = i / 5, k = i - 5*v;
        s_emb8[v*8 + k] = emb[i];
    }
    for (int i = tid; i < HID*LAT; i += NT) {          // w3T[c][k]
        const int k = i / 5, c = i - 5*k;
        s_w3t[c*132 + k] = ew3[i];
    }
    for (int i = tid; i < LAT*HID; i += NT) s_dw1[i] = dw1[i];
    for (int i = tid; i < HID*DIN; i += NT) {          // dw2T[c][k]
        const int k = i / 14, c = i - 14*k;
        s_dw2t[c*132 + k] = dw2[i];
    }
    if (tid < HID) { s_b1[tid] = eb1[tid]; s_b2[tid] = eb2[tid]; s_db1[tid] = db1[tid]; }
    if (tid < LAT) s_b3[tid] = eb3[tid];
    if (tid < DIN) s_db2[tid] = db2[tid];
    __syncthreads();

    // ||emb||^2 per code — same fenced unfused chain as round 6, stored in slot 5
    if (tid < VOCAB) {
        const float* e8 = &s_emb8[tid*8];
        float p0 = e8[0]*e8[0];
        float p1 = e8[1]*e8[1];
        float p2 = e8[2]*e8[2];
        float p3 = e8[3]*e8[3];
        float p4 = e8[4]*e8[4];
        float e = p0 + p1; FENCE(e);
        e = e + p2; FENCE(e);
        e = e + p3; FENCE(e);
        e = e + p4; FENCE(e);
        s_emb8[tid*8 + 5] = e;
    }

    // ---- layer 1: h1 = relu(x @ w1 + b1), single-acc ascending fmaf chain ----
    {
        const int r  = tid >> 2;     // 0..127
        const int q4 = tid & 3;
        const float* xrow = x + (size_t)(r_base + r) * DIN;
        float xr[DIN];
        #pragma unroll
        for (int k = 0; k < DIN; k += 2) {
            float2 v = *reinterpret_cast<const float2*>(xrow + k);
            xr[k] = v.x; xr[k+1] = v.y;
        }
        for (int cc = 0; cc < HID/4; ++cc) {
            const int c = q4 + 4*cc;
            const float4 wq0 = *reinterpret_cast<const float4*>(&s_w1t[c*16 + 0]);
            const float4 wq1 = *reinterpret_cast<const float4*>(&s_w1t[c*16 + 4]);
            const float4 wq2 = *reinterpret_cast<const float4*>(&s_w1t[c*16 + 8]);
            const float4 wq3 = *reinterpret_cast<const float4*>(&s_w1t[c*16 + 12]);
            const float w[14] = {wq0.x,wq0.y,wq0.z,wq0.w, wq1.x,wq1.y,wq1.z,wq1.w,
                                 wq2.x,wq2.y,wq2.z,wq2.w, wq3.x,wq3.y};
            float s = 0.f;
            #pragma unroll
            for (int k = 0; k < DIN; ++k) { s = fmaf(xr[k], w[k], s); FENCE(s); }
            s = s + s_b1[c]; FENCE(s);
            s_h[r*HS + c] = fmaxf(s, 0.f);
        }
    }
    __syncthreads();   // layer-1 done; W1T region is dead from here on

    // ---- layer 2: h2 = relu(h1 @ w2 + b2), dual-acc (even/odd k) as round 6 ----
    {
        const int trow = tid >> 4;   // 0..31
        const int tcol = tid & 15;   // 0..15
        const int r0 = trow * 4, c0 = tcol * 8;
        float accE[4][8], accO[4][8];
        #pragma unroll
        for (int i = 0; i < 4; ++i)
            #pragma unroll
            for (int j = 0; j < 8; ++j) { accE[i][j] = 0.f; accO[i][j] = 0.f; }

        for (int k = 0; k < HID; k += 2) {
            float hvE[4], hvO[4];
            #pragma unroll
            for (int i = 0; i < 4; ++i) {
                const float2 hp = *reinterpret_cast<const float2*>(&s_h[(r0+i)*HS + k]);
                hvE[i] = hp.x; hvO[i] = hp.y;
            }
            float4 waE = *reinterpret_cast<const float4*>(&s_w2[k*HID + c0]);
            float4 wbE = *reinterpret_cast<const float4*>(&s_w2[k*HID + c0 + 4]);
            float4 waO = *reinterpret_cast<const float4*>(&s_w2[(k+1)*HID + c0]);
            float4 wbO = *reinterpret_cast<const float4*>(&s_w2[(k+1)*HID + c0 + 4]);
            float wE[8] = {waE.x, waE.y, waE.z, waE.w, wbE.x, wbE.y, wbE.z, wbE.w};
            float wO[8] = {waO.x, waO.y, waO.z, waO.w, wbO.x, wbO.y, wbO.z, wbO.w};
            #pragma unroll
            for (int i = 0; i < 4; ++i)
                #pragma unroll
                for (int j = 0; j < 8; ++j) {
                    accE[i][j] = fmaf(hvE[i], wE[j], accE[i][j]); FENCE(accE[i][j]);
                    accO[i][j] = fmaf(hvO[i], wO[j], accO[i][j]); FENCE(accO[i][j]);
                }
        }
        __syncthreads();   // all h1 reads complete before overwrite
        #pragma unroll
        for (int i = 0; i < 4; ++i)
            #pragma unroll
            for (int j = 0; j < 8; ++j) {
                const int c = c0 + j;
                float s = accE[i][j] + accO[i][j]; FENCE(s);
                s = s + s_b2[c]; FENCE(s);
                s_h[(r0+i)*HS + c] = fmaxf(s, 0.f);
            }
    }
    __syncthreads();

    // ---- layer 3: q = h2 @ w3 + b3, same ascending fenced chain (b128 quads) ----
    for (int oi = tid; oi < BR*LAT; oi += NT) {
        const int r = oi / LAT;
        const int c = oi - r*LAT;
        float s = 0.f;
        for (int kq = 0; kq < HID; kq += 4) {
            const float4 hq = *reinterpret_cast<const float4*>(&s_h[r*HS + kq]);
            const float4 wq = *reinterpret_cast<const float4*>(&s_w3t[c*132 + kq]);
            s = fmaf(hq.x, wq.x, s); FENCE(s);
            s = fmaf(hq.y, wq.y, s); FENCE(s);
            s = fmaf(hq.z, wq.z, s); FENCE(s);
            s = fmaf(hq.w, wq.w, s); FENCE(s);
        }
        s = s + s_b3[c]; FENCE(s);
        s_q[r*LAT + c] = s;
    }
    if (tid < VOCAB) s_hist[tid] = 0u;
    __syncthreads();

    // ---- VQ: argmin over 256 codes (descending-k dot, same fenced score) ----
    float loss_local = 0.f;
    {
        const int r  = tid >> 2;
        const int q4 = tid & 3;
        float qv[LAT];
        #pragma unroll
        for (int k = 0; k < LAT; ++k) qv[k] = s_q[r*LAT + k];

        float qp0 = qv[0]*qv[0];
        float qp1 = qv[1]*qv[1];
        float qp2 = qv[2]*qv[2];
        float qp3 = qv[3]*qv[3];
        float qp4 = qv[4]*qv[4];
        float qq = qp0 + qp1; FENCE(qq);
        qq = qq + qp2; FENCE(qq);
        qq = qq + qp3; FENCE(qq);
        qq = qq + qp4; FENCE(qq);

        float bd = 3.4e38f; int bv = VOCAB;
        for (int ii = 0; ii < VOCAB/4; ++ii) {
            const int v = q4 + 4*ii;   // interleaved -> conflict-free 4-group pattern
            const float4 elo = *reinterpret_cast<const float4*>(&s_emb8[v*8]);
            const float4 ehi = *reinterpret_cast<const float4*>(&s_emb8[v*8 + 4]);
            float dot = 0.f;
            dot = fmaf(qv[4], ehi.x, dot); FENCE(dot);
            dot = fmaf(qv[3], elo.w, dot); FENCE(dot);
            dot = fmaf(qv[2], elo.z, dot); FENCE(dot);
            dot = fmaf(qv[1], elo.y, dot); FENCE(dot);
            dot = fmaf(qv[0], elo.x, dot); FENCE(dot);
            float twodot = 2.0f * dot; FENCE(twodot);
            float t1 = qq - twodot; FENCE(t1);
            float sc = t1 + ehi.y; FENCE(sc);
            const bool better = (sc < bd) || (sc == bd && v < bv);
            bd = better ? sc : bd;
            bv = better ? v  : bv;
        }
        #pragma unroll
        for (int m = 1; m <= 2; m <<= 1) {   // reduce across the 4 lanes of this row
            const float od = __shfl_xor(bd, m);
            const int   ov = __shfl_xor(bv, m);
            const bool better = (od < bd) || (od == bd && ov < bv);
            bd = better ? od : bd;
            bv = better ? ov : bv;
        }
        if (q4 == 0) {
            s_idx[r] = bv;
            atomicAdd(&s_hist[bv], 1u);
            float ls = 0.f;
            #pragma unroll
            for (int k = 0; k < LAT; ++k) {
                const float d = qv[k] - s_emb8[bv*8 + k];
                ls = fmaf(d, d, ls);
            }
            loss_local = ls;
            // qe = q + (e - q)  (same expression/rounding as round-6 decoder)
            #pragma unroll
            for (int k = 0; k < 4; ++k) {
                const float ev = s_emb8[bv*8 + k];
                s_qe4[r*4 + k] = qv[k] + (ev - qv[k]);
            }
            {
                const float ev = s_emb8[bv*8 + 4];
                s_qe1[r] = qv[4] + (ev - qv[4]);
            }
        }
    }

    // ---- block-reduce loss, flush hist ----
    {
        float s = loss_local;
        #pragma unroll
        for (int off = 32; off > 0; off >>= 1) s += __shfl_down(s, off);
        if ((tid & 63) == 0) s_red[tid >> 6] = s;
    }
    __syncthreads();
    if (tid == 0) {
        float s = 0.f;
        #pragma unroll
        for (int w = 0; w < NT/64; ++w) s += s_red[w];
        atomicAdd(loss_sum, (double)s);
    }
    if (tid < VOCAB) {
        const unsigned c = s_hist[tid];
        if (c) atomicAdd(&hist_g[tid], c);
    }

    // ---- one-hot write (coalesced float2) + indices ----
    {
        float* oh = out + OH_OFF;
        const int rr0 = tid >> 7;       // 0..3
        const int c0  = (tid & 127) * 2;
        for (int it = 0; it < BR/4; ++it) {
            const int r = it*4 + rr0;
            const int best = s_idx[r];
            float2 v;
            v.x = (c0     == best) ? 1.f : 0.f;
            v.y = (c0 + 1 == best) ? 1.f : 0.f;
            *reinterpret_cast<float2*>(oh + (size_t)(r_base + r)*VOCAB + c0) = v;
        }
        if (tid < BR) out[IDX_OFF + r_base + tid] = (float)s_idx[tid];
    }

    // ---- decoder layer 1: h3 = relu(qe @ dw1 + db1); qe hoisted per row ----
    {
        const int r  = tid >> 2;
        const int q4 = tid & 3;
        const float4 qlo = *reinterpret_cast<const float4*>(&s_qe4[r*4]);
        const float qe4v = s_qe1[r];
        for (int cc = 0; cc < HID/4; ++cc) {
            const int c = q4 + 4*cc;
            float s = 0.f;
            s = fmaf(qlo.x, s_dw1[0*HID + c], s);
            s = fmaf(qlo.y, s_dw1[1*HID + c], s);
            s = fmaf(qlo.z, s_dw1[2*HID + c], s);
            s = fmaf(qlo.w, s_dw1[3*HID + c], s);
            s = fmaf(qe4v,  s_dw1[4*HID + c], s);
            s_h[r*HS + c] = fmaxf(s + s_db1[c], 0.f);
        }
    }
    __syncthreads();

    // ---- decoder layer 2: out = h3 @ dw2 + db2 (b128 quads, same chain) ----
    for (int oi = tid; oi < BR*DIN; oi += NT) {
        const int r = oi / DIN;
        const int c = oi - r*DIN;
        float s = 0.f;
        for (int kq = 0; kq < HID; kq += 4) {
            const float4 hq = *reinterpret_cast<const float4*>(&s_h[r*HS + kq]);
            const float4 wq = *reinterpret_cast<const float4*>(&s_dw2t[c*132 + kq]);
            s = fmaf(hq.x, wq.x, s);
            s = fmaf(hq.y, wq.y, s);
            s = fmaf(hq.z, wq.z, s);
            s = fmaf(hq.w, wq.w, s);
        }
        out[(size_t)r_base*DIN + oi] = s + s_db2[c];
    }
}

__global__ void vq_init(double* loss, unsigned int* hist)
{
    if (threadIdx.x == 0) *loss = 0.0;
    if (threadIdx.x < VOCAB) hist[threadIdx.x] = 0u;
}

__global__ void vq_final(const double* __restrict__ loss,
                         const unsigned int* __restrict__ hist,
                         float* __restrict__ out)
{
    #pragma clang fp contract(off)
    __shared__ float red[4];
    const int t = threadIdx.x;   // 256 threads
    const float em = (float)hist[t] / (float)NROWS;
    float s = em * logf(em + 1e-10f);
    #pragma unroll
    for (int off = 32; off > 0; off >>= 1) s += __shfl_down(s, off);
    if ((t & 63) == 0) red[t >> 6] = s;
    __syncthreads();
    if (t == 0) {
        const float tot = red[0] + red[1] + red[2] + red[3];
        out[PERP_OFF] = expf(-tot);
        out[LOSS_OFF] = 1.25f * (float)(*loss / (double)((size_t)NROWS * LAT));
    }
}

extern "C" void kernel_launch(void* const* d_in, const int* in_sizes, int n_in,
                              void* d_out, int out_size, void* d_ws, size_t ws_size,
                              hipStream_t stream)
{
    const float* x   = (const float*)d_in[0];
    const float* ew1 = (const float*)d_in[1];
    const float* eb1 = (const float*)d_in[2];
    const float* ew2 = (const float*)d_in[3];
    const float* eb2 = (const float*)d_in[4];
    const float* ew3 = (const float*)d_in[5];
    const float* eb3 = (const float*)d_in[6];
    const float* emb = (const float*)d_in[7];
    const float* dw1 = (const float*)d_in[8];
    const float* db1 = (const float*)d_in[9];
    const float* dw2 = (const float*)d_in[10];
    const float* db2 = (const float*)d_in[11];
    float* out = (float*)d_out;

    double* loss = (double*)d_ws;
    unsigned int* hist = (unsigned int*)((char*)d_ws + 8);

    hipFuncSetAttribute(reinterpret_cast<const void*>(vqvae_main),
                        hipFuncAttributeMaxDynamicSharedMemorySize, SMEM_BYTES);

    vq_init<<<1, 256, 0, stream>>>(loss, hist);
    vqvae_main<<<NROWS / BR, NT, SMEM_BYTES, stream>>>(
        x, ew1, eb1, ew2, eb2, ew3, eb3, emb, dw1, db1, dw2, db2,
        out, loss, hist);
    vq_final<<<1, 256, 0, stream>>>(loss, hist, out);
}

// Round 8
// 1072.431 us; speedup vs baseline: 1.5146x; 1.1188x over previous
//
#include <hip/hip_runtime.h>
#include <cstdint>
#include <cstddef>

#define NROWS 524288
#define DIN 14
#define HID 128
#define LAT 5
#define VOCAB 256
#define BR 64           // rows per block
#define NT 512          // threads per block
#define HS 132          // LDS stride for h tile (%4==0 -> b64/b128 aligned)

// Zero-instruction fence: pins a float in a VGPR so the chain order is exact.
#define FENCE(v) asm volatile("" : "+v"(v))

// d_out layout (floats), concatenated reference outputs:
static constexpr size_t LOSS_OFF = 7340032;                 // quant_loss scalar
static constexpr size_t PERP_OFF = 7340033;                 // perplexity scalar
static constexpr size_t OH_OFF   = 7340034;                 // min_encodings [N,256]
static constexpr size_t IDX_OFF  = 141557762;               // min_encoding_indices [N,1]

// ---- LDS layout (float offsets) ----
// WBUF region (8192 floats): w2 K-half [64][128] during layer 2;
// repurposed for ALL phase-2 data after layer 2 completes.
static constexpr int OFF_WBUF = 0;
static constexpr int OFF_EMB8 = 0;        // [256][8]: e0..e4, ee, pad, pad = 2048
static constexpr int OFF_W3T  = 2048;     // [5 c][132 k] = 660 (pad 664)
static constexpr int OFF_DW1T = 2712;     // [128 c][8 k] = 1024
static constexpr int OFF_DW2T = 3736;     // [14 c][132 k] = 1848
static constexpr int OFF_B3   = 5584;     // 8
static constexpr int OFF_DB1  = 5592;     // 128
static constexpr int OFF_DB2  = 5720;     // 16
static constexpr int OFF_Q    = 5736;     // [64][5] = 320
static constexpr int OFF_QE4  = 6056;     // [64][4] = 256 (b128-readable)
static constexpr int OFF_QE1  = 6312;     // [64]
static constexpr int OFF_IDX  = 6376;     // 64 ints
static constexpr int OFF_HIST = 6440;     // 256 u32
static constexpr int OFF_RED  = 6696;     // 16 f   (ends 6712 <= 8192)
static constexpr int OFF_H    = 8192;     // [64][HS] = 8448 -> ends 16640
static constexpr int OFF_W1T  = 16640;    // [128 c][20 k] = 2560 -> ends 19200
static constexpr int OFF_B1   = 19200;    // 128
static constexpr int OFF_B2   = 19328;    // 128
static constexpr int SMEM_FLOATS = 19456;
static constexpr int SMEM_BYTES  = SMEM_FLOATS * 4;   // 77,824 B -> 2 blocks/CU
static_assert(SMEM_BYTES <= 80*1024, "need <=80KB for 2 blocks/CU");
static_assert((OFF_W3T%4)==0 && (OFF_DW1T%4)==0 && (OFF_DW2T%4)==0 &&
              (OFF_QE4%4)==0 && (OFF_H%4)==0 && (OFF_W1T%4)==0, "align");

__global__ __launch_bounds__(NT, 4)
void vqvae_main(const float* __restrict__ x,
                const float* __restrict__ ew1, const float* __restrict__ eb1,
                const float* __restrict__ ew2, const float* __restrict__ eb2,
                const float* __restrict__ ew3, const float* __restrict__ eb3,
                const float* __restrict__ emb,
                const float* __restrict__ dw1, const float* __restrict__ db1,
                const float* __restrict__ dw2, const float* __restrict__ db2,
                float* __restrict__ out,
                double* __restrict__ loss_sum,
                unsigned int* __restrict__ hist_g)
{
    #pragma clang fp contract(off)

    extern __shared__ float smem[];
    float* s_wbuf = smem + OFF_WBUF;
    float* s_h    = smem + OFF_H;
    float* s_w1t  = smem + OFF_W1T;
    float* s_b1   = smem + OFF_B1;
    float* s_b2   = smem + OFF_B2;
    float* s_emb8 = smem + OFF_EMB8;
    float* s_w3t  = smem + OFF_W3T;
    float* s_dw1t = smem + OFF_DW1T;
    float* s_dw2t = smem + OFF_DW2T;
    float* s_b3   = smem + OFF_B3;
    float* s_db1  = smem + OFF_DB1;
    float* s_db2  = smem + OFF_DB2;
    float* s_q    = smem + OFF_Q;
    float* s_qe4  = smem + OFF_QE4;
    float* s_qe1  = smem + OFF_QE1;
    int*   s_idx  = reinterpret_cast<int*>(smem + OFF_IDX);
    unsigned int* s_hist = reinterpret_cast<unsigned int*>(smem + OFF_HIST);
    float* s_red  = smem + OFF_RED;

    const int tid = threadIdx.x;
    const int r_base = blockIdx.x * BR;

    // ---- phase 1 staging: w2 half A (k=0..63), w1T, b1, b2 ----
    {
        float4* wb4 = reinterpret_cast<float4*>(s_wbuf);
        const float4* w2g = reinterpret_cast<const float4*>(ew2);
        for (int i = tid; i < 2048; i += NT) wb4[i] = w2g[i];
        for (int i = tid; i < DIN*HID; i += NT) {      // w1T[c][k]
            const int k = i >> 7, c = i & 127;
            s_w1t[c*20 + k] = ew1[i];
        }
        if (tid < HID) { s_b1[tid] = eb1[tid]; s_b2[tid] = eb2[tid]; }
    }
    __syncthreads();

    // ---- layer 1: h1 = relu(x @ w1 + b1), single-acc ascending fmaf chain ----
    {
        const int r  = tid >> 3;     // 0..63
        const int q8 = tid & 7;
        const float* xrow = x + (size_t)(r_base + r) * DIN;
        float xr[DIN];
        #pragma unroll
        for (int k = 0; k < DIN; k += 2) {
            float2 v = *reinterpret_cast<const float2*>(xrow + k);
            xr[k] = v.x; xr[k+1] = v.y;
        }
        for (int cc = 0; cc < HID/8; ++cc) {
            const int c = q8 + 8*cc;
            const float4 wq0 = *reinterpret_cast<const float4*>(&s_w1t[c*20 + 0]);
            const float4 wq1 = *reinterpret_cast<const float4*>(&s_w1t[c*20 + 4]);
            const float4 wq2 = *reinterpret_cast<const float4*>(&s_w1t[c*20 + 8]);
            const float4 wq3 = *reinterpret_cast<const float4*>(&s_w1t[c*20 + 12]);
            const float w[14] = {wq0.x,wq0.y,wq0.z,wq0.w, wq1.x,wq1.y,wq1.z,wq1.w,
                                 wq2.x,wq2.y,wq2.z,wq2.w, wq3.x,wq3.y};
            float s = 0.f;
            #pragma unroll
            for (int k = 0; k < DIN; ++k) { s = fmaf(xr[k], w[k], s); FENCE(s); }
            s = s + s_b1[c]; FENCE(s);
            s_h[r*HS + c] = fmaxf(s, 0.f);
        }
    }
    __syncthreads();

    // ---- layer 2: h2 = relu(h1 @ w2 + b2), dual-acc (even/odd k) chains,
    //      K split into two staged halves; chain order identical to round 7 ----
    {
        const int trow = tid >> 4;   // 0..31
        const int tcol = tid & 15;   // 0..15
        const int r0 = trow * 2, c0 = tcol * 8;
        float accE[2][8], accO[2][8];
        #pragma unroll
        for (int i = 0; i < 2; ++i)
            #pragma unroll
            for (int j = 0; j < 8; ++j) { accE[i][j] = 0.f; accO[i][j] = 0.f; }

        #pragma unroll 1
        for (int pass = 0; pass < 2; ++pass) {
            const int kbase = pass * 64;
            for (int kk = 0; kk < 64; kk += 2) {
                float hvE[2], hvO[2];
                #pragma unroll
                for (int i = 0; i < 2; ++i) {
                    const float2 hp = *reinterpret_cast<const float2*>(&s_h[(r0+i)*HS + kbase + kk]);
                    hvE[i] = hp.x; hvO[i] = hp.y;
                }
                float4 waE = *reinterpret_cast<const float4*>(&s_wbuf[kk*HID + c0]);
                float4 wbE = *reinterpret_cast<const float4*>(&s_wbuf[kk*HID + c0 + 4]);
                float4 waO = *reinterpret_cast<const float4*>(&s_wbuf[(kk+1)*HID + c0]);
                float4 wbO = *reinterpret_cast<const float4*>(&s_wbuf[(kk+1)*HID + c0 + 4]);
                float wE[8] = {waE.x, waE.y, waE.z, waE.w, wbE.x, wbE.y, wbE.z, wbE.w};
                float wO[8] = {waO.x, waO.y, waO.z, waO.w, wbO.x, wbO.y, wbO.z, wbO.w};
                #pragma unroll
                for (int i = 0; i < 2; ++i)
                    #pragma unroll
                    for (int j = 0; j < 8; ++j) {
                        accE[i][j] = fmaf(hvE[i], wE[j], accE[i][j]); FENCE(accE[i][j]);
                        accO[i][j] = fmaf(hvO[i], wO[j], accO[i][j]); FENCE(accO[i][j]);
                    }
            }
            __syncthreads();   // pass reads complete
            if (pass == 0) {   // restage w2 half B (k=64..127)
                float4* wb4 = reinterpret_cast<float4*>(s_wbuf);
                const float4* w2g = reinterpret_cast<const float4*>(ew2);
                for (int i = tid; i < 2048; i += NT) wb4[i] = w2g[i + 2048];
                __syncthreads();
            }
        }
        // all h1 reads done (barrier above); write h2
        #pragma unroll
        for (int i = 0; i < 2; ++i)
            #pragma unroll
            for (int j = 0; j < 8; ++j) {
                const int c = c0 + j;
                float s = accE[i][j] + accO[i][j]; FENCE(s);
                s = s + s_b2[c]; FENCE(s);
                s_h[(r0+i)*HS + c] = fmaxf(s, 0.f);
            }
    }
    __syncthreads();

    // ---- phase 2 staging into (now dead) WBUF: emb8, w3T, dw1T, dw2T, biases ----
    {
        for (int i = tid; i < VOCAB*LAT; i += NT) {    // emb8[v][k]
            const int v = i / 5, k = i - 5*v;
            s_emb8[v*8 + k] = emb[i];
        }
        for (int i = tid; i < HID*LAT; i += NT) {      // w3T[c][k]
            const int k = i / 5, c = i - 5*k;
            s_w3t[c*132 + k] = ew3[i];
        }
        for (int i = tid; i < LAT*HID; i += NT) {      // dw1T[c][k]
            const int k = i >> 7, c = i & 127;
            s_dw1t[c*8 + k] = dw1[i];
        }
        for (int i = tid; i < HID*DIN; i += NT) {      // dw2T[c][k]
            const int k = i / 14, c = i - 14*k;
            s_dw2t[c*132 + k] = dw2[i];
        }
        if (tid < LAT) s_b3[tid] = eb3[tid];
        if (tid < HID) s_db1[tid] = db1[tid];
        if (tid < DIN) s_db2[tid] = db2[tid];
        if (tid < VOCAB) s_hist[tid] = 0u;
    }
    __syncthreads();

    // ---- ee (fenced chain, slot 5) + layer 3: q = h2 @ w3 + b3 ----
    if (tid < VOCAB) {
        const float* e8 = &s_emb8[tid*8];
        float p0 = e8[0]*e8[0];
        float p1 = e8[1]*e8[1];
        float p2 = e8[2]*e8[2];
        float p3 = e8[3]*e8[3];
        float p4 = e8[4]*e8[4];
        float e = p0 + p1; FENCE(e);
        e = e + p2; FENCE(e);
        e = e + p3; FENCE(e);
        e = e + p4; FENCE(e);
        s_emb8[tid*8 + 5] = e;
    }
    if (tid < BR*LAT) {
        const int r = tid / LAT;
        const int c = tid - r*LAT;
        float s = 0.f;
        for (int kq = 0; kq < HID; kq += 4) {
            const float4 hq = *reinterpret_cast<const float4*>(&s_h[r*HS + kq]);
            const float4 wq = *reinterpret_cast<const float4*>(&s_w3t[c*132 + kq]);
            s = fmaf(hq.x, wq.x, s); FENCE(s);
            s = fmaf(hq.y, wq.y, s); FENCE(s);
            s = fmaf(hq.z, wq.z, s); FENCE(s);
            s = fmaf(hq.w, wq.w, s); FENCE(s);
        }
        s = s + s_b3[c]; FENCE(s);
        s_q[r*LAT + c] = s;
    }
    __syncthreads();

    // ---- VQ: argmin over 256 codes, 8 threads per row (descending-k dot) ----
    float loss_local = 0.f;
    {
        const int r  = tid >> 3;
        const int q8 = tid & 7;
        float qv[LAT];
        #pragma unroll
        for (int k = 0; k < LAT; ++k) qv[k] = s_q[r*LAT + k];

        float qp0 = qv[0]*qv[0];
        float qp1 = qv[1]*qv[1];
        float qp2 = qv[2]*qv[2];
        float qp3 = qv[3]*qv[3];
        float qp4 = qv[4]*qv[4];
        float qq = qp0 + qp1; FENCE(qq);
        qq = qq + qp2; FENCE(qq);
        qq = qq + qp3; FENCE(qq);
        qq = qq + qp4; FENCE(qq);

        float bd = 3.4e38f; int bv = VOCAB;
        for (int ii = 0; ii < VOCAB/8; ++ii) {
            const int v = q8 + 8*ii;
            const float4 elo = *reinterpret_cast<const float4*>(&s_emb8[v*8]);
            const float4 ehi = *reinterpret_cast<const float4*>(&s_emb8[v*8 + 4]);
            float dot = 0.f;
            dot = fmaf(qv[4], ehi.x, dot); FENCE(dot);
            dot = fmaf(qv[3], elo.w, dot); FENCE(dot);
            dot = fmaf(qv[2], elo.z, dot); FENCE(dot);
            dot = fmaf(qv[1], elo.y, dot); FENCE(dot);
            dot = fmaf(qv[0], elo.x, dot); FENCE(dot);
            float twodot = 2.0f * dot; FENCE(twodot);
            float t1 = qq - twodot; FENCE(t1);
            float sc = t1 + ehi.y; FENCE(sc);
            const bool better = (sc < bd) || (sc == bd && v < bv);
            bd = better ? sc : bd;
            bv = better ? v  : bv;
        }
        #pragma unroll
        for (int m = 1; m <= 4; m <<= 1) {   // reduce across the 8 lanes of this row
            const float od = __shfl_xor(bd, m);
            const int   ov = __shfl_xor(bv, m);
            const bool better = (od < bd) || (od == bd && ov < bv);
            bd = better ? od : bd;
            bv = better ? ov : bv;
        }
        if (q8 == 0) {
            s_idx[r] = bv;
            atomicAdd(&s_hist[bv], 1u);
            float ls = 0.f;
            #pragma unroll
            for (int k = 0; k < LAT; ++k) {
                const float d = qv[k] - s_emb8[bv*8 + k];
                ls = fmaf(d, d, ls);
            }
            loss_local = ls;
            // qe = q + (e - q)  (same expression/rounding as rounds 6/7)
            #pragma unroll
            for (int k = 0; k < 4; ++k) {
                const float ev = s_emb8[bv*8 + k];
                s_qe4[r*4 + k] = qv[k] + (ev - qv[k]);
            }
            {
                const float ev = s_emb8[bv*8 + 4];
                s_qe1[r] = qv[4] + (ev - qv[4]);
            }
        }
    }

    // ---- block-reduce loss ----
    {
        float s = loss_local;
        #pragma unroll
        for (int off = 32; off > 0; off >>= 1) s += __shfl_down(s, off);
        if ((tid & 63) == 0) s_red[tid >> 6] = s;
    }
    __syncthreads();
    if (tid == 0) {
        float s = 0.f;
        #pragma unroll
        for (int w = 0; w < NT/64; ++w) s += s_red[w];
        atomicAdd(loss_sum, (double)s);
    }
    if (tid < VOCAB) {
        const unsigned c = s_hist[tid];
        if (c) atomicAdd(&hist_g[tid], c);
    }

    // ---- one-hot write (coalesced float2) + indices ----
    {
        float* oh = out + OH_OFF;
        const int rr0 = tid >> 7;       // 0..3
        const int c0  = (tid & 127) * 2;
        for (int it = 0; it < BR/4; ++it) {
            const int r = it*4 + rr0;
            const int best = s_idx[r];
            float2 v;
            v.x = (c0     == best) ? 1.f : 0.f;
            v.y = (c0 + 1 == best) ? 1.f : 0.f;
            *reinterpret_cast<float2*>(oh + (size_t)(r_base + r)*VOCAB + c0) = v;
        }
        if (tid < BR) out[IDX_OFF + r_base + tid] = (float)s_idx[tid];
    }

    // ---- decoder layer 1: h3 = relu(qe @ dw1 + db1) ----
    {
        const int r  = tid >> 3;
        const int q8 = tid & 7;
        const float4 qlo = *reinterpret_cast<const float4*>(&s_qe4[r*4]);
        const float qe4v = s_qe1[r];
        for (int cc = 0; cc < HID/8; ++cc) {
            const int c = q8 + 8*cc;
            const float4 wq = *reinterpret_cast<const float4*>(&s_dw1t[c*8]);
            const float w4 = s_dw1t[c*8 + 4];
            float s = 0.f;
            s = fmaf(qlo.x, wq.x, s);
            s = fmaf(qlo.y, wq.y, s);
            s = fmaf(qlo.z, wq.z, s);
            s = fmaf(qlo.w, wq.w, s);
            s = fmaf(qe4v,  w4,   s);
            s_h[r*HS + c] = fmaxf(s + s_db1[c], 0.f);
        }
    }
    __syncthreads();

    // ---- decoder layer 2: out = h3 @ dw2 + db2 (b128 quads) ----
    for (int oi = tid; oi < BR*DIN; oi += NT) {
        const int r = oi / DIN;
        const int c = oi - r*DIN;
        float s = 0.f;
        for (int kq = 0; kq < HID; kq += 4) {
            const float4 hq = *reinterpret_cast<const float4*>(&s_h[r*HS + kq]);
            const float4 wq = *reinterpret_cast<const float4*>(&s_dw2t[c*132 + kq]);
            s = fmaf(hq.x, wq.x, s);
            s = fmaf(hq.y, wq.y, s);
            s = fmaf(hq.z, wq.z, s);
            s = fmaf(hq.w, wq.w, s);
        }
        out[(size_t)r_base*DIN + oi] = s + s_db2[c];
    }
}

__global__ void vq_init(double* loss, unsigned int* hist)
{
    if (threadIdx.x == 0) *loss = 0.0;
    if (threadIdx.x < VOCAB) hist[threadIdx.x] = 0u;
}

__global__ void vq_final(const double* __restrict__ loss,
                         const unsigned int* __restrict__ hist,
                         float* __restrict__ out)
{
    #pragma clang fp contract(off)
    __shared__ float red[4];
    const int t = threadIdx.x;   // 256 threads
    const float em = (float)hist[t] / (float)NROWS;
    float s = em * logf(em + 1e-10f);
    #pragma unroll
    for (int off = 32; off > 0; off >>= 1) s += __shfl_down(s, off);
    if ((t & 63) == 0) red[t >> 6] = s;
    __syncthreads();
    if (t == 0) {
        const float tot = red[0] + red[1] + red[2] + red[3];
        out[PERP_OFF] = expf(-tot);
        out[LOSS_OFF] = 1.25f * (float)(*loss / (double)((size_t)NROWS * LAT));
    }
}

extern "C" void kernel_launch(void* const* d_in, const int* in_sizes, int n_in,
                              void* d_out, int out_size, void* d_ws, size_t ws_size,
                              hipStream_t stream)
{
    const float* x   = (const float*)d_in[0];
    const float* ew1 = (const float*)d_in[1];
    const float* eb1 = (const float*)d_in[2];
    const float* ew2 = (const float*)d_in[3];
    const float* eb2 = (const float*)d_in[4];
    const float* ew3 = (const float*)d_in[5];
    const float* eb3 = (const float*)d_in[6];
    const float* emb = (const float*)d_in[7];
    const float* dw1 = (const float*)d_in[8];
    const float* db1 = (const float*)d_in[9];
    const float* dw2 = (const float*)d_in[10];
    const float* db2 = (const float*)d_in[11];
    float* out = (float*)d_out;

    double* loss = (double*)d_ws;
    unsigned int* hist = (unsigned int*)((char*)d_ws + 8);

    hipFuncSetAttribute(reinterpret_cast<const void*>(vqvae_main),
                        hipFuncAttributeMaxDynamicSharedMemorySize, SMEM_BYTES);

    vq_init<<<1, 256, 0, stream>>>(loss, hist);
    vqvae_main<<<NROWS / BR, NT, SMEM_BYTES, stream>>>(
        x, ew1, eb1, ew2, eb2, ew3, eb3, emb, dw1, db1, dw2, db2,
        out, loss, hist);
    vq_final<<<1, 256, 0, stream>>>(loss, hist, out);
}

// Round 9
// 1027.447 us; speedup vs baseline: 1.5809x; 1.0438x over previous
//
#include <hip/hip_runtime.h>
#include <cstdint>
#include <cstddef>

#define NROWS 524288
#define DIN 14
#define HID 128
#define LAT 5
#define VOCAB 256
#define BR 64           // rows per block
#define NT 512          // threads per block
#define HS 132          // LDS stride for h tile (%4==0 -> b64/b128 aligned)

// Zero-instruction fence: pins a float in a VGPR so the chain order is exact.
#define FENCE(v) asm volatile("" : "+v"(v))

// d_out layout (floats), concatenated reference outputs:
static constexpr size_t LOSS_OFF = 7340032;                 // quant_loss scalar
static constexpr size_t PERP_OFF = 7340033;                 // perplexity scalar
static constexpr size_t OH_OFF   = 7340034;                 // min_encodings [N,256]
static constexpr size_t IDX_OFF  = 141557762;               // min_encoding_indices [N,1]

// ---- LDS layout (float offsets) ----
// WBUF region (8192 floats): w2 K-half [64][128] during layer 2;
// repurposed for ALL phase-2 data after layer 2 completes.
static constexpr int OFF_WBUF = 0;
static constexpr int OFF_EMB8 = 0;        // [256][8]: e0..e4, ee, pad, pad = 2048
static constexpr int OFF_W3T  = 2048;     // [5 c][132 k] = 660 (pad 664)
static constexpr int OFF_DW1T = 2712;     // [128 c][8 k] = 1024
static constexpr int OFF_DW2T = 3736;     // [14 c][132 k] = 1848
static constexpr int OFF_B3   = 5584;     // 8
static constexpr int OFF_DB1  = 5592;     // 128
static constexpr int OFF_DB2  = 5720;     // 16
static constexpr int OFF_Q    = 5736;     // [64][5] = 320
static constexpr int OFF_QE4  = 6056;     // [64][4] = 256 (b128-readable)
static constexpr int OFF_QE1  = 6312;     // [64]
static constexpr int OFF_IDX  = 6376;     // 64 ints
static constexpr int OFF_HIST = 6440;     // 256 u32
static constexpr int OFF_RED  = 6696;     // 16 f   (ends 6712 <= 8192)
static constexpr int OFF_H    = 8192;     // [64][HS] = 8448 -> ends 16640
static constexpr int OFF_W1T  = 16640;    // [128 c][20 k] = 2560 -> ends 19200
static constexpr int OFF_B1   = 19200;    // 128
static constexpr int OFF_B2   = 19328;    // 128
static constexpr int SMEM_FLOATS = 19456;
static constexpr int SMEM_BYTES  = SMEM_FLOATS * 4;   // 77,824 B -> 2 blocks/CU
static_assert(SMEM_BYTES <= 80*1024, "need <=80KB for 2 blocks/CU");
static_assert((OFF_W3T%4)==0 && (OFF_DW1T%4)==0 && (OFF_DW2T%4)==0 &&
              (OFF_QE4%4)==0 && (OFF_H%4)==0 && (OFF_W1T%4)==0, "align");

__global__ __launch_bounds__(NT, 4)
void vqvae_main(const float* __restrict__ x,
                const float* __restrict__ ew1, const float* __restrict__ eb1,
                const float* __restrict__ ew2, const float* __restrict__ eb2,
                const float* __restrict__ ew3, const float* __restrict__ eb3,
                const float* __restrict__ emb,
                const float* __restrict__ dw1, const float* __restrict__ db1,
                const float* __restrict__ dw2, const float* __restrict__ db2,
                float* __restrict__ out,
                double* __restrict__ loss_sum,
                unsigned int* __restrict__ hist_g)
{
    #pragma clang fp contract(off)

    extern __shared__ float smem[];
    float* s_wbuf = smem + OFF_WBUF;
    float* s_h    = smem + OFF_H;
    float* s_w1t  = smem + OFF_W1T;
    float* s_b1   = smem + OFF_B1;
    float* s_b2   = smem + OFF_B2;
    float* s_emb8 = smem + OFF_EMB8;
    float* s_w3t  = smem + OFF_W3T;
    float* s_dw1t = smem + OFF_DW1T;
    float* s_dw2t = smem + OFF_DW2T;
    float* s_b3   = smem + OFF_B3;
    float* s_db1  = smem + OFF_DB1;
    float* s_db2  = smem + OFF_DB2;
    float* s_q    = smem + OFF_Q;
    float* s_qe4  = smem + OFF_QE4;
    float* s_qe1  = smem + OFF_QE1;
    int*   s_idx  = reinterpret_cast<int*>(smem + OFF_IDX);
    unsigned int* s_hist = reinterpret_cast<unsigned int*>(smem + OFF_HIST);
    float* s_red  = smem + OFF_RED;

    const int tid = threadIdx.x;
    const int r_base = blockIdx.x * BR;

    // ---- phase 1 staging: w2 half A (k=0..63), w1T, b1, b2 ----
    {
        float4* wb4 = reinterpret_cast<float4*>(s_wbuf);
        const float4* w2g = reinterpret_cast<const float4*>(ew2);
        for (int i = tid; i < 2048; i += NT) wb4[i] = w2g[i];
        for (int i = tid; i < DIN*HID; i += NT) {      // w1T[c][k]
            const int k = i >> 7, c = i & 127;
            s_w1t[c*20 + k] = ew1[i];
        }
        if (tid < HID) { s_b1[tid] = eb1[tid]; s_b2[tid] = eb2[tid]; }
    }
    __syncthreads();

    // ---- layer 1: h1 = relu(x @ w1 + b1), single-acc ascending fmaf chain ----
    {
        const int r  = tid >> 3;     // 0..63
        const int q8 = tid & 7;
        const float* xrow = x + (size_t)(r_base + r) * DIN;
        float xr[DIN];
        #pragma unroll
        for (int k = 0; k < DIN; k += 2) {
            float2 v = *reinterpret_cast<const float2*>(xrow + k);
            xr[k] = v.x; xr[k+1] = v.y;
        }
        for (int cc = 0; cc < HID/8; ++cc) {
            const int c = q8 + 8*cc;
            const float4 wq0 = *reinterpret_cast<const float4*>(&s_w1t[c*20 + 0]);
            const float4 wq1 = *reinterpret_cast<const float4*>(&s_w1t[c*20 + 4]);
            const float4 wq2 = *reinterpret_cast<const float4*>(&s_w1t[c*20 + 8]);
            const float4 wq3 = *reinterpret_cast<const float4*>(&s_w1t[c*20 + 12]);
            const float w[14] = {wq0.x,wq0.y,wq0.z,wq0.w, wq1.x,wq1.y,wq1.z,wq1.w,
                                 wq2.x,wq2.y,wq2.z,wq2.w, wq3.x,wq3.y};
            float s = 0.f;
            #pragma unroll
            for (int k = 0; k < DIN; ++k) { s = fmaf(xr[k], w[k], s); FENCE(s); }
            s = s + s_b1[c]; FENCE(s);
            s_h[r*HS + c] = fmaxf(s, 0.f);
        }
    }
    __syncthreads();

    // ---- layer 2: h2 = relu(h1 @ w2 + b2), 256 threads x (4 rows x 8 cols),
    //      dual-acc (even/odd k) ascending chains — per-element arithmetic
    //      IDENTICAL to rounds 6-8. Idle threads zero-fill the one-hot output. ----
    {
        const int trow = tid >> 4;   // 0..15 (tid<256)
        const int tcol = tid & 15;
        const int r0 = trow * 4, c0 = tcol * 8;
        float accE[4][8], accO[4][8];
        #pragma unroll
        for (int i = 0; i < 4; ++i)
            #pragma unroll
            for (int j = 0; j < 8; ++j) { accE[i][j] = 0.f; accO[i][j] = 0.f; }

        // ---- pass 0 (k = 0..63) ∥ one-hot zero-fill by threads 256..511 ----
        if (tid < 256) {
            for (int kk = 0; kk < 64; kk += 4) {
                float4 h4[4];
                #pragma unroll
                for (int i = 0; i < 4; ++i)
                    h4[i] = *reinterpret_cast<const float4*>(&s_h[(r0+i)*HS + kk]);
                {   // k = kk (even), kk+1 (odd)
                    float4 waE = *reinterpret_cast<const float4*>(&s_wbuf[kk*HID + c0]);
                    float4 wbE = *reinterpret_cast<const float4*>(&s_wbuf[kk*HID + c0 + 4]);
                    float4 waO = *reinterpret_cast<const float4*>(&s_wbuf[(kk+1)*HID + c0]);
                    float4 wbO = *reinterpret_cast<const float4*>(&s_wbuf[(kk+1)*HID + c0 + 4]);
                    float wE[8] = {waE.x,waE.y,waE.z,waE.w, wbE.x,wbE.y,wbE.z,wbE.w};
                    float wO[8] = {waO.x,waO.y,waO.z,waO.w, wbO.x,wbO.y,wbO.z,wbO.w};
                    #pragma unroll
                    for (int i = 0; i < 4; ++i)
                        #pragma unroll
                        for (int j = 0; j < 8; ++j) {
                            accE[i][j] = fmaf(h4[i].x, wE[j], accE[i][j]); FENCE(accE[i][j]);
                            accO[i][j] = fmaf(h4[i].y, wO[j], accO[i][j]); FENCE(accO[i][j]);
                        }
                }
                {   // k = kk+2 (even), kk+3 (odd)
                    float4 waE = *reinterpret_cast<const float4*>(&s_wbuf[(kk+2)*HID + c0]);
                    float4 wbE = *reinterpret_cast<const float4*>(&s_wbuf[(kk+2)*HID + c0 + 4]);
                    float4 waO = *reinterpret_cast<const float4*>(&s_wbuf[(kk+3)*HID + c0]);
                    float4 wbO = *reinterpret_cast<const float4*>(&s_wbuf[(kk+3)*HID + c0 + 4]);
                    float wE[8] = {waE.x,waE.y,waE.z,waE.w, wbE.x,wbE.y,wbE.z,wbE.w};
                    float wO[8] = {waO.x,waO.y,waO.z,waO.w, wbO.x,wbO.y,wbO.z,wbO.w};
                    #pragma unroll
                    for (int i = 0; i < 4; ++i)
                        #pragma unroll
                        for (int j = 0; j < 8; ++j) {
                            accE[i][j] = fmaf(h4[i].z, wE[j], accE[i][j]); FENCE(accE[i][j]);
                            accO[i][j] = fmaf(h4[i].w, wO[j], accO[i][j]); FENCE(accO[i][j]);
                        }
                }
            }
        } else {
            // zero-fill one-hot [64 rows][256 cols] as float4 (poisoned each call)
            float4* oh4 = reinterpret_cast<float4*>(out + OH_OFF + (size_t)r_base*VOCAB);
            const float4 z = {0.f, 0.f, 0.f, 0.f};
            const int t = tid - 256;
            #pragma unroll
            for (int it = 0; it < 16; ++it) oh4[it*256 + t] = z;
        }
        __syncthreads();   // pass-0 w2 reads done
        {   // restage w2 half B (k=64..127)
            float4* wb4 = reinterpret_cast<float4*>(s_wbuf);
            const float4* w2g = reinterpret_cast<const float4*>(ew2);
            for (int i = tid; i < 2048; i += NT) wb4[i] = w2g[i + 2048];
        }
        __syncthreads();
        // ---- pass 1 (k = 64..127) ----
        if (tid < 256) {
            for (int kk = 0; kk < 64; kk += 4) {
                float4 h4[4];
                #pragma unroll
                for (int i = 0; i < 4; ++i)
                    h4[i] = *reinterpret_cast<const float4*>(&s_h[(r0+i)*HS + 64 + kk]);
                {
                    float4 waE = *reinterpret_cast<const float4*>(&s_wbuf[kk*HID + c0]);
                    float4 wbE = *reinterpret_cast<const float4*>(&s_wbuf[kk*HID + c0 + 4]);
                    float4 waO = *reinterpret_cast<const float4*>(&s_wbuf[(kk+1)*HID + c0]);
                    float4 wbO = *reinterpret_cast<const float4*>(&s_wbuf[(kk+1)*HID + c0 + 4]);
                    float wE[8] = {waE.x,waE.y,waE.z,waE.w, wbE.x,wbE.y,wbE.z,wbE.w};
                    float wO[8] = {waO.x,waO.y,waO.z,waO.w, wbO.x,wbO.y,wbO.z,wbO.w};
                    #pragma unroll
                    for (int i = 0; i < 4; ++i)
                        #pragma unroll
                        for (int j = 0; j < 8; ++j) {
                            accE[i][j] = fmaf(h4[i].x, wE[j], accE[i][j]); FENCE(accE[i][j]);
                            accO[i][j] = fmaf(h4[i].y, wO[j], accO[i][j]); FENCE(accO[i][j]);
                        }
                }
                {
                    float4 waE = *reinterpret_cast<const float4*>(&s_wbuf[(kk+2)*HID + c0]);
                    float4 wbE = *reinterpret_cast<const float4*>(&s_wbuf[(kk+2)*HID + c0 + 4]);
                    float4 waO = *reinterpret_cast<const float4*>(&s_wbuf[(kk+3)*HID + c0]);
                    float4 wbO = *reinterpret_cast<const float4*>(&s_wbuf[(kk+3)*HID + c0 + 4]);
                    float wE[8] = {waE.x,waE.y,waE.z,waE.w, wbE.x,wbE.y,wbE.z,wbE.w};
                    float wO[8] = {waO.x,waO.y,waO.z,waO.w, wbO.x,wbO.y,wbO.z,wbO.w};
                    #pragma unroll
                    for (int i = 0; i < 4; ++i)
                        #pragma unroll
                        for (int j = 0; j < 8; ++j) {
                            accE[i][j] = fmaf(h4[i].z, wE[j], accE[i][j]); FENCE(accE[i][j]);
                            accO[i][j] = fmaf(h4[i].w, wO[j], accO[i][j]); FENCE(accO[i][j]);
                        }
                }
            }
        }
        __syncthreads();   // pass-1 reads done; h1 + wbuf now dead
        if (tid < 256) {
            #pragma unroll
            for (int i = 0; i < 4; ++i)
                #pragma unroll
                for (int j = 0; j < 8; ++j) {
                    const int c = c0 + j;
                    float s = accE[i][j] + accO[i][j]; FENCE(s);
                    s = s + s_b2[c]; FENCE(s);
                    s_h[(r0+i)*HS + c] = fmaxf(s, 0.f);
                }
        }
    }

    // ---- phase 2 staging into (now dead) WBUF: emb8, w3T, dw1T, dw2T, biases ----
    {
        for (int i = tid; i < VOCAB*LAT; i += NT) {    // emb8[v][k]
            const int v = i / 5, k = i - 5*v;
            s_emb8[v*8 + k] = emb[i];
        }
        for (int i = tid; i < HID*LAT; i += NT) {      // w3T[c][k]
            const int k = i / 5, c = i - 5*k;
            s_w3t[c*132 + k] = ew3[i];
        }
        for (int i = tid; i < LAT*HID; i += NT) {      // dw1T[c][k]
            const int k = i >> 7, c = i & 127;
            s_dw1t[c*8 + k] = dw1[i];
        }
        for (int i = tid; i < HID*DIN; i += NT) {      // dw2T[c][k]
            const int k = i / 14, c = i - 14*k;
            s_dw2t[c*132 + k] = dw2[i];
        }
        if (tid < LAT) s_b3[tid] = eb3[tid];
        if (tid < HID) s_db1[tid] = db1[tid];
        if (tid < DIN) s_db2[tid] = db2[tid];
        if (tid < VOCAB) s_hist[tid] = 0u;
    }
    __syncthreads();

    // ---- ee (fenced chain, slot 5) + layer 3: q = h2 @ w3 + b3 ----
    if (tid < VOCAB) {
        const float* e8 = &s_emb8[tid*8];
        float p0 = e8[0]*e8[0];
        float p1 = e8[1]*e8[1];
        float p2 = e8[2]*e8[2];
        float p3 = e8[3]*e8[3];
        float p4 = e8[4]*e8[4];
        float e = p0 + p1; FENCE(e);
        e = e + p2; FENCE(e);
        e = e + p3; FENCE(e);
        e = e + p4; FENCE(e);
        s_emb8[tid*8 + 5] = e;
    }
    if (tid < BR*LAT) {
        const int r = tid / LAT;
        const int c = tid - r*LAT;
        float s = 0.f;
        for (int kq = 0; kq < HID; kq += 4) {
            const float4 hq = *reinterpret_cast<const float4*>(&s_h[r*HS + kq]);
            const float4 wq = *reinterpret_cast<const float4*>(&s_w3t[c*132 + kq]);
            s = fmaf(hq.x, wq.x, s); FENCE(s);
            s = fmaf(hq.y, wq.y, s); FENCE(s);
            s = fmaf(hq.z, wq.z, s); FENCE(s);
            s = fmaf(hq.w, wq.w, s); FENCE(s);
        }
        s = s + s_b3[c]; FENCE(s);
        s_q[r*LAT + c] = s;
    }
    __syncthreads();

    // ---- VQ: argmin over 256 codes, 8 threads per row (descending-k dot) ----
    float loss_local = 0.f;
    {
        const int r  = tid >> 3;
        const int q8 = tid & 7;
        float qv[LAT];
        #pragma unroll
        for (int k = 0; k < LAT; ++k) qv[k] = s_q[r*LAT + k];

        float qp0 = qv[0]*qv[0];
        float qp1 = qv[1]*qv[1];
        float qp2 = qv[2]*qv[2];
        float qp3 = qv[3]*qv[3];
        float qp4 = qv[4]*qv[4];
        float qq = qp0 + qp1; FENCE(qq);
        qq = qq + qp2; FENCE(qq);
        qq = qq + qp3; FENCE(qq);
        qq = qq + qp4; FENCE(qq);

        float bd = 3.4e38f; int bv = VOCAB;
        for (int ii = 0; ii < VOCAB/8; ++ii) {
            const int v = q8 + 8*ii;
            const float4 elo = *reinterpret_cast<const float4*>(&s_emb8[v*8]);
            const float4 ehi = *reinterpret_cast<const float4*>(&s_emb8[v*8 + 4]);
            float dot = 0.f;
            dot = fmaf(qv[4], ehi.x, dot); FENCE(dot);
            dot = fmaf(qv[3], elo.w, dot); FENCE(dot);
            dot = fmaf(qv[2], elo.z, dot); FENCE(dot);
            dot = fmaf(qv[1], elo.y, dot); FENCE(dot);
            dot = fmaf(qv[0], elo.x, dot); FENCE(dot);
            float twodot = 2.0f * dot; FENCE(twodot);
            float t1 = qq - twodot; FENCE(t1);
            float sc = t1 + ehi.y; FENCE(sc);
            const bool better = (sc < bd) || (sc == bd && v < bv);
            bd = better ? sc : bd;
            bv = better ? v  : bv;
        }
        #pragma unroll
        for (int m = 1; m <= 4; m <<= 1) {   // reduce across the 8 lanes of this row
            const float od = __shfl_xor(bd, m);
            const int    ov = __shfl_xor(bv, m);
            const bool better = (od < bd) || (od == bd && ov < bv);
            bd = better ? od : bd;
            bv = better ? ov : bv;
        }
        if (q8 == 0) {
            s_idx[r] = bv;
            atomicAdd(&s_hist[bv], 1u);
            float ls = 0.f;
            #pragma unroll
            for (int k = 0; k < LAT; ++k) {
                const float d = qv[k] - s_emb8[bv*8 + k];
                ls = fmaf(d, d, ls);
            }
            loss_local = ls;
            // one-hot "1" write (zero-fill done during layer 2; WAW ordered by
            // the intervening barriers' vmcnt drain)
            out[OH_OFF + (size_t)(r_base + r)*VOCAB + bv] = 1.0f;
            out[IDX_OFF + r_base + r] = (float)bv;
            // qe = q + (e - q)  (same expression/rounding as rounds 6-8)
            #pragma unroll
            for (int k = 0; k < 4; ++k) {
                const float ev = s_emb8[bv*8 + k];
                s_qe4[r*4 + k] = qv[k] + (ev - qv[k]);
            }
            {
                const float ev = s_emb8[bv*8 + 4];
                s_qe1[r] = qv[4] + (ev - qv[4]);
            }
        }
    }

    // ---- block-reduce loss ----
    {
        float s = loss_local;
        #pragma unroll
        for (int off = 32; off > 0; off >>= 1) s += __shfl_down(s, off);
        if ((tid & 63) == 0) s_red[tid >> 6] = s;
    }
    __syncthreads();
    if (tid == 0) {
        float s = 0.f;
        #pragma unroll
        for (int w = 0; w < NT/64; ++w) s += s_red[w];
        atomicAdd(loss_sum, (double)s);
    }
    if (tid < VOCAB) {
        const unsigned c = s_hist[tid];
        if (c) atomicAdd(&hist_g[tid], c);
    }

    // ---- decoder layer 1: h3 = relu(qe @ dw1 + db1) ----
    {
        const int r  = tid >> 3;
        const int q8 = tid & 7;
        const float4 qlo = *reinterpret_cast<const float4*>(&s_qe4[r*4]);
        const float qe4v = s_qe1[r];
        for (int cc = 0; cc < HID/8; ++cc) {
            const int c = q8 + 8*cc;
            const float4 wq = *reinterpret_cast<const float4*>(&s_dw1t[c*8]);
            const float w4 = s_dw1t[c*8 + 4];
            float s = 0.f;
            s = fmaf(qlo.x, wq.x, s);
            s = fmaf(qlo.y, wq.y, s);
            s = fmaf(qlo.z, wq.z, s);
            s = fmaf(qlo.w, wq.w, s);
            s = fmaf(qe4v,  w4,   s);
            s_h[r*HS + c] = fmaxf(s + s_db1[c], 0.f);
        }
    }
    __syncthreads();

    // ---- decoder layer 2: out = h3 @ dw2 + db2 (b128 quads) ----
    for (int oi = tid; oi < BR*DIN; oi += NT) {
        const int r = oi / DIN;
        const int c = oi - r*DIN;
        float s = 0.f;
        for (int kq = 0; kq < HID; kq += 4) {
            const float4 hq = *reinterpret_cast<const float4*>(&s_h[r*HS + kq]);
            const float4 wq = *reinterpret_cast<const float4*>(&s_dw2t[c*132 + kq]);
            s = fmaf(hq.x, wq.x, s);
            s = fmaf(hq.y, wq.y, s);
            s = fmaf(hq.z, wq.z, s);
            s = fmaf(hq.w, wq.w, s);
        }
        out[(size_t)r_base*DIN + oi] = s + s_db2[c];
    }
}

__global__ void vq_init(double* loss, unsigned int* hist)
{
    if (threadIdx.x == 0) *loss = 0.0;
    if (threadIdx.x < VOCAB) hist[threadIdx.x] = 0u;
}

__global__ void vq_final(const double* __restrict__ loss,
                         const unsigned int* __restrict__ hist,
                         float* __restrict__ out)
{
    #pragma clang fp contract(off)
    __shared__ float red[4];
    const int t = threadIdx.x;   // 256 threads
    const float em = (float)hist[t] / (float)NROWS;
    float s = em * logf(em + 1e-10f);
    #pragma unroll
    for (int off = 32; off > 0; off >>= 1) s += __shfl_down(s, off);
    if ((t & 63) == 0) red[t >> 6] = s;
    __syncthreads();
    if (t == 0) {
        const float tot = red[0] + red[1] + red[2] + red[3];
        out[PERP_OFF] = expf(-tot);
        out[LOSS_OFF] = 1.25f * (float)(*loss / (double)((size_t)NROWS * LAT));
    }
}

extern "C" void kernel_launch(void* const* d_in, const int* in_sizes, int n_in,
                              void* d_out, int out_size, void* d_ws, size_t ws_size,
                              hipStream_t stream)
{
    const float* x   = (const float*)d_in[0];
    const float* ew1 = (const float*)d_in[1];
    const float* eb1 = (const float*)d_in[2];
    const float* ew2 = (const float*)d_in[3];
    const float* eb2 = (const float*)d_in[4];
    const float* ew3 = (const float*)d_in[5];
    const float* eb3 = (const float*)d_in[6];
    const float* emb = (const float*)d_in[7];
    const float* dw1 = (const float*)d_in[8];
    const float* db1 = (const float*)d_in[9];
    const float* dw2 = (const float*)d_in[10];
    const float* db2 = (const float*)d_in[11];
    float* out = (float*)d_out;

    double* loss = (double*)d_ws;
    unsigned int* hist = (unsigned int*)((char*)d_ws + 8);

    hipFuncSetAttribute(reinterpret_cast<const void*>(vqvae_main),
                        hipFuncAttributeMaxDynamicSharedMemorySize, SMEM_BYTES);

    vq_init<<<1, 256, 0, stream>>>(loss, hist);
    vqvae_main<<<NROWS / BR, NT, SMEM_BYTES, stream>>>(
        x, ew1, eb1, ew2, eb2, ew3, eb3, emb, dw1, db1, dw2, db2,
        out, loss, hist);
    vq_final<<<1, 256, 0, stream>>>(loss, hist, out);
}